// Round 1
// 121.360 us; speedup vs baseline: 1.0094x; 1.0094x over previous
//
#include <hip/hip_runtime.h>

// ROI bilinear pooling: img (1,200,200,512) fp32, rois (1,300,4) int32 [x,y,w,h]
// out (1,300,7,7,512) fp32.
//
// v2: one block per (roi, py, px-pair). 128 threads x float4 = 512 channels.
//   - 8 independent dwordx4 loads in flight per thread (2x MLP vs v1)
//   - y-side coordinate math + both row base addresses shared across the pair
//   - rois fetched once per block as int4 (s_load_dwordx4)
//   - grid 300*7*4 = 8400 blocks (p==3 handles the lone px=6)

#define IMG_W 200
#define NCH   512
#define BPR   28   // blocks per roi: 7 py * 4 px-pairs

__global__ __launch_bounds__(128) void roi_bilinear_kernel(
    const float* __restrict__ img,
    const int*   __restrict__ rois,
    float*       __restrict__ out)
{
    int bid = blockIdx.x;            // r*28 + py*4 + p
    int r   = bid / BPR;
    int rem = bid - r * BPR;
    int py  = rem >> 2;
    int p   = rem & 3;
    int px0 = p << 1;                // 0,2,4,6
    int px1 = px0 + 1;               // 1,3,5,(7=invalid)

    int4 rv = *(const int4*)(rois + 4 * r);   // wave-uniform -> scalar load
    int x0 = rv.x, y0 = rv.y, w = rv.z, h = rv.w;

    // Strict IEEE fp32, op-for-op identical to the jax reference (no fma
    // contraction): scale = h/7.0f; ys = y0 + py*scale.
    float sy = __fdiv_rn((float)h, 7.0f);
    float sx = __fdiv_rn((float)w, 7.0f);

    // y side: shared by both px positions of the pair.
    float ys = __fadd_rn((float)y0, __fmul_rn((float)py, sy));
    int   ty = (int)floorf(ys);
    float fy = __fsub_rn(ys, (float)ty);
    int   by = min(ty + 1, y0 + h - 1);

    // x side, position A (px0)
    float xsa = __fadd_rn((float)x0, __fmul_rn((float)px0, sx));
    int   txa = (int)floorf(xsa);
    float fxa = __fsub_rn(xsa, (float)txa);
    int   bxa = min(txa + 1, x0 + w - 1);

    // x side, position B (px1)
    float xsb = __fadd_rn((float)x0, __fmul_rn((float)px1, sx));
    int   txb = (int)floorf(xsb);
    float fxb = __fsub_rn(xsb, (float)txb);
    int   bxb = min(txb + 1, x0 + w - 1);

    const float* rowT = img + (size_t)(ty * IMG_W) * NCH;
    const float* rowB = img + (size_t)(by * IMG_W) * NCH;

    int t = threadIdx.x;   // 0..127, one float4 of channels each

    // Issue all 8 loads before any use: 8 dwordx4 outstanding per thread.
    const float4* p00a = (const float4*)(rowT + (size_t)txa * NCH);
    const float4* p01a = (const float4*)(rowT + (size_t)bxa * NCH);
    const float4* p10a = (const float4*)(rowB + (size_t)txa * NCH);
    const float4* p11a = (const float4*)(rowB + (size_t)bxa * NCH);
    float4 v00a = p00a[t];
    float4 v01a = p01a[t];
    float4 v10a = p10a[t];
    float4 v11a = p11a[t];

    bool haveB = (px1 < 7);          // wave-uniform branch
    float4 v00b, v01b, v10b, v11b;
    if (haveB) {
        const float4* p00b = (const float4*)(rowT + (size_t)txb * NCH);
        const float4* p01b = (const float4*)(rowT + (size_t)bxb * NCH);
        const float4* p10b = (const float4*)(rowB + (size_t)txb * NCH);
        const float4* p11b = (const float4*)(rowB + (size_t)bxb * NCH);
        v00b = p00b[t];
        v01b = p01b[t];
        v10b = p10b[t];
        v11b = p11b[t];
    }

    float gy = 1.0f - fy;

    {   // position A blend + store
        float gx = 1.0f - fxa;
        float4 o;
        o.x = gy * (gx * v00a.x + fxa * v01a.x) + fy * (gx * v10a.x + fxa * v11a.x);
        o.y = gy * (gx * v00a.y + fxa * v01a.y) + fy * (gx * v10a.y + fxa * v11a.y);
        o.z = gy * (gx * v00a.z + fxa * v01a.z) + fy * (gx * v10a.z + fxa * v11a.z);
        o.w = gy * (gx * v00a.w + fxa * v01a.w) + fy * (gx * v10a.w + fxa * v11a.w);
        float4* po = (float4*)(out + (size_t)(r * 49 + py * 7 + px0) * NCH);
        po[t] = o;
    }

    if (haveB) {   // position B blend + store
        float gx = 1.0f - fxb;
        float4 o;
        o.x = gy * (gx * v00b.x + fxb * v01b.x) + fy * (gx * v10b.x + fxb * v11b.x);
        o.y = gy * (gx * v00b.y + fxb * v01b.y) + fy * (gx * v10b.y + fxb * v11b.y);
        o.z = gy * (gx * v00b.z + fxb * v01b.z) + fy * (gx * v10b.z + fxb * v11b.z);
        o.w = gy * (gx * v00b.w + fxb * v01b.w) + fy * (gx * v10b.w + fxb * v11b.w);
        float4* po = (float4*)(out + (size_t)(r * 49 + py * 7 + px1) * NCH);
        po[t] = o;
    }
}

extern "C" void kernel_launch(void* const* d_in, const int* in_sizes, int n_in,
                              void* d_out, int out_size, void* d_ws, size_t ws_size,
                              hipStream_t stream)
{
    const float* img  = (const float*)d_in[0];   // 1*200*200*512 fp32
    const int*   rois = (const int*)d_in[1];     // 1*300*4 int32
    float*       out  = (float*)d_out;           // 1*300*7*7*512 fp32

    const int nroi = in_sizes[1] / 4;            // 300
    dim3 grid(nroi * BPR);                       // 8400 blocks
    dim3 block(128);
    roi_bilinear_kernel<<<grid, block, 0, stream>>>(img, rois, out);
}